// Round 2
// baseline (694.301 us; speedup 1.0000x reference)
//
#include <hip/hip_runtime.h>
#include <math.h>

// LocalAggregationLoss, R3: invert the gather.
//   Scattered-512B gather measured ~0.79 TB/s (structure-invariant across two
//   different MLP pipelines) vs 6.3 TB/s streaming. Unique touched rows =
//   172 MB of the 512 MB bank -> streaming the WHOLE bank (85us) beats
//   gathering 40% of it (220us+).
// Pipeline (all state in d_ws, ~8 MB):
//   k_init : head[] = -1, dacc[] = 0
//   k_vnorm: vtab[b] = normalize(codes[b])
//   k_build: per-row linked list via atomicExch(head[idx], e); next[e] = old
//            (entry id e encodes (list,b,k) implicitly: e = list*B*K + b*K + k)
//   k_main : 2048 blocks stream the bank sequentially (full 512 MB, coalesced
//            1KB/wave-instr, unroll x4); per row walk the chain: dot vs
//            vtab[b] (L2-resident), exp, atomicAdd dacc[list*B+b]
//   k_fin  : out[b] = log(d1[b]) - log(d2[b])
// Falls back to the R2 gather kernel if ws_size < 16 MB.

constexpr int   DIM   = 128;
constexpr int   KN    = 200;
constexpr int   NBANK = 1000000;
constexpr float INV_T = 1.0f / 0.07f;

// ---------------- R3 kernels ----------------

__global__ __launch_bounds__(256)
void k_init(int* __restrict__ head, float* __restrict__ dacc, int batch)
{
    const int i = blockIdx.x * blockDim.x + threadIdx.x;
    const int n = gridDim.x * blockDim.x;
    for (int r = i; r < NBANK; r += n) head[r] = -1;
    if (i < 2 * batch) dacc[i] = 0.0f;
}

__global__ __launch_bounds__(128)
void k_vnorm(const float* __restrict__ codes, float* __restrict__ vtab)
{
    const int b = blockIdx.x;
    const int t = threadIdx.x;            // 128 threads = 2 waves
    __shared__ float w[2];
    float c  = codes[b * DIM + t];
    float ss = c * c;
    #pragma unroll
    for (int m = 32; m > 0; m >>= 1) ss += __shfl_xor(ss, m, 64);
    if ((t & 63) == 0) w[t >> 6] = ss;
    __syncthreads();
    const float rn = 1.0f / sqrtf(w[0] + w[1]);
    vtab[b * DIM + t] = c * rn;
}

__global__ __launch_bounds__(256)
void k_build(const int* __restrict__ idx_bg, const int* __restrict__ idx_cl,
             int* __restrict__ head, int* __restrict__ next, int batch)
{
    const int n  = 2 * batch * KN;
    const int bk = batch * KN;
    for (int e = blockIdx.x * blockDim.x + threadIdx.x; e < n;
         e += gridDim.x * blockDim.x) {
        const int r = (e < bk) ? idx_bg[e] : idx_cl[e - bk];
        next[e] = atomicExch(&head[r], e);
    }
}

__global__ __launch_bounds__(256)
void k_main(const float* __restrict__ bank, const int* __restrict__ head,
            const int* __restrict__ next, const float* __restrict__ vtab,
            float* __restrict__ dacc, int batch)
{
    const int seg  = blockIdx.x;          // 2048 segments x 512 rows
    const int tid  = threadIdx.x;
    const int base = seg * 512;
    const int bk   = batch * KN;

    __shared__ int s_head[512];
    for (int i = tid; i < 512; i += 256) {
        const int r = base + i;
        s_head[i] = (r < NBANK) ? head[r] : -1;
    }
    __syncthreads();

    const int w    = tid >> 6;            // wave 0..3
    const int lane = tid & 63;
    const int half = lane >> 5;           // two rows per wave instruction
    const int sl   = lane & 31;           // 32 lanes x 16B = one 512B row

    // wave w owns local row-pairs {8j+2w, 8j+2w+1}, j = 0..63 -> the block's
    // combined access stream is the contiguous 256KB segment.
    auto ldrow = [&](int j) -> float4 {
        const int r = base + 8 * j + 2 * w + half;
        return (r < NBANK) ? ((const float4*)(bank + (size_t)r * DIM))[sl]
                           : make_float4(0.f, 0.f, 0.f, 0.f);
    };

    // walk row (base+lr)'s chain; e is uniform across the 32 lanes of a half.
    auto chase = [&](int j, float4 x) {
        const int lr = 8 * j + 2 * w + half;
        int e = s_head[lr];
        while (__any(e >= 0)) {
            const bool act = (e >= 0);
            int   en = -1, di = 0;
            float4 vb = make_float4(0.f, 0.f, 0.f, 0.f);
            if (act) {
                const int list = (e >= bk) ? 1 : 0;
                const int b    = (e - list * bk) / KN;     // k not needed
                di = list * batch + b;
                vb = ((const float4*)(vtab + (size_t)b * DIM))[sl];
                en = next[e];
            }
            float d = x.x * vb.x + x.y * vb.y + x.z * vb.z + x.w * vb.w;
            d += __shfl_xor(d, 16, 32);
            d += __shfl_xor(d, 8, 32);
            d += __shfl_xor(d, 4, 32);
            d += __shfl_xor(d, 2, 32);
            d += __shfl_xor(d, 1, 32);
            if (act && sl == 0) atomicAdd(&dacc[di], __expf(d * INV_T));
            e = en;
        }
    };

    // unroll x4: 4KB of independent streaming loads in flight per wave while
    // chains (latency-bound, mostly empty) drain.
    for (int j = 0; j < 64; j += 4) {
        float4 xa = ldrow(j);
        float4 xb = ldrow(j + 1);
        float4 xc = ldrow(j + 2);
        float4 xd = ldrow(j + 3);
        chase(j,     xa);
        chase(j + 1, xb);
        chase(j + 2, xc);
        chase(j + 3, xd);
    }
}

__global__ __launch_bounds__(256)
void k_fin(const float* __restrict__ dacc, float* __restrict__ out, int batch)
{
    const int b = blockIdx.x * blockDim.x + threadIdx.x;
    if (b < batch) out[b] = logf(dacc[b]) - logf(dacc[batch + b]);
}

// ---------------- fallback (R2 gather pipeline) ----------------

constexpr int HALF  = 100;
constexpr int TROWS = 4;
constexpr int NT    = HALF / TROWS;

typedef const __attribute__((address_space(1))) void gvoid_t;
typedef __attribute__((address_space(3))) void lvoid_t;

__global__ __launch_bounds__(256, 6)
void lal_fallback(const float* __restrict__ codes,
                  const float* __restrict__ bank,
                  const int*   __restrict__ idx_bg,
                  const int*   __restrict__ idx_cl,
                  float*       __restrict__ out)
{
    const int b    = blockIdx.x;
    const int tid  = threadIdx.x;
    const int w    = tid >> 6;
    const int lane = tid & 63;

    __shared__ alignas(16) float v[DIM];
    __shared__ int   s_idx[4 * HALF];
    __shared__ alignas(16) float tiles[4][3][TROWS * DIM];
    __shared__ float wsum[4];
    __shared__ float red[4];
    __shared__ float s_rnorm;

    const int* ip    = (w < 2) ? idx_bg : idx_cl;
    const int  kbase = (w & 1) * HALF;
    for (int k = lane; k < HALF; k += 64)
        s_idx[w * HALF + k] = ip[b * KN + kbase + k];

    float c  = (tid < DIM) ? codes[b * DIM + tid] : 0.0f;
    float ss = c * c;
    #pragma unroll
    for (int m = 32; m > 0; m >>= 1) ss += __shfl_xor(ss, m, 64);
    if ((tid & 63) == 0) wsum[tid >> 6] = ss;
    __syncthreads();
    if (tid == 0) {
        float t = wsum[0] + wsum[1] + wsum[2] + wsum[3];
        s_rnorm = 1.0f / sqrtf(t);
    }
    __syncthreads();
    if (tid < DIM) v[tid] = c * s_rnorm;
    __syncthreads();

    const int s = lane & 15;
    const int r = lane >> 4;
    const float4 vv0 = ((const float4*)v)[s];
    const float4 vv1 = ((const float4*)v)[s + 16];

    const float* bank_lane = bank + (lane & 31) * 4;
    const int*   midx = &s_idx[w * HALF];
    float* const tb   = &tiles[w][0][0];
    float sum = 0.0f;

    auto STAGE = [&](int t, int bsel) {
        int r0 = midx[4 * t     + (lane >> 5)];
        int r1 = midx[4 * t + 2 + (lane >> 5)];
        const float* g0 = bank_lane + (size_t)r0 * DIM;
        const float* g1 = bank_lane + (size_t)r1 * DIM;
        float* d0 = tb + bsel * (TROWS * DIM);
        float* d1 = d0 + 2 * DIM;
        __builtin_amdgcn_global_load_lds((gvoid_t*)g0, (lvoid_t*)d0, 16, 0, 0);
        __builtin_amdgcn_global_load_lds((gvoid_t*)g1, (lvoid_t*)d1, 16, 0, 0);
    };
    auto COMPUTE = [&](int bsel) {
        const float4* T = (const float4*)(tb + bsel * (TROWS * DIM));
        float4 x0 = T[r * 32 + s];
        float4 x1 = T[r * 32 + s + 16];
        float d = x0.x * vv0.x + x0.y * vv0.y + x0.z * vv0.z + x0.w * vv0.w
                + x1.x * vv1.x + x1.y * vv1.y + x1.z * vv1.z + x1.w * vv1.w;
        d += __shfl_xor(d, 1, 16);
        d += __shfl_xor(d, 2, 16);
        d += __shfl_xor(d, 4, 16);
        d += __shfl_xor(d, 8, 16);
        float e = __expf(d * INV_T);
        if (s == 0) sum += e;
    };

    STAGE(0, 0);
    STAGE(1, 1);
    int bsel = 0;
    for (int t = 0; t < NT - 2; ++t) {
        STAGE(t + 2, (bsel + 2) % 3);
        asm volatile("s_waitcnt vmcnt(4)" ::: "memory");
        COMPUTE(bsel);
        __builtin_amdgcn_sched_barrier(0);
        bsel = (bsel + 1) % 3;
    }
    asm volatile("s_waitcnt vmcnt(2)" ::: "memory");
    COMPUTE(bsel);
    bsel = (bsel + 1) % 3;
    asm volatile("s_waitcnt vmcnt(0)" ::: "memory");
    COMPUTE(bsel);

    #pragma unroll
    for (int m = 32; m > 0; m >>= 1) sum += __shfl_xor(sum, m, 64);
    if (lane == 0) red[w] = sum;
    __syncthreads();
    if (tid == 0)
        out[b] = logf(red[0] + red[1]) - logf(red[2] + red[3]);
}

// ---------------- launcher ----------------

extern "C" void kernel_launch(void* const* d_in, const int* in_sizes, int n_in,
                              void* d_out, int out_size, void* d_ws, size_t ws_size,
                              hipStream_t stream)
{
    const float* codes  = (const float*)d_in[0];
    const float* bank   = (const float*)d_in[1];
    const int*   idx_bg = (const int*)d_in[2];
    const int*   idx_cl = (const int*)d_in[3];
    float*       out    = (float*)d_out;

    const int batch = in_sizes[0] / DIM;   // 1024

    if (ws_size >= (size_t)(16u << 20)) {
        // ws layout: head 4MB | next 4MB | vtab 4MB | dacc
        char*  ws   = (char*)d_ws;
        int*   head = (int*)(ws);
        int*   next = (int*)(ws + (4u << 20));
        float* vtab = (float*)(ws + (8u << 20));
        float* dacc = (float*)(ws + (12u << 20));

        k_init <<<2048, 256, 0, stream>>>(head, dacc, batch);
        k_vnorm<<<batch, 128, 0, stream>>>(codes, vtab);
        k_build<<<(2 * batch * KN + 255) / 256, 256, 0, stream>>>(
            idx_bg, idx_cl, head, next, batch);
        k_main <<<2048, 256, 0, stream>>>(bank, head, next, vtab, dacc, batch);
        k_fin  <<<(batch + 255) / 256, 256, 0, stream>>>(dacc, out, batch);
    } else {
        lal_fallback<<<batch, 256, 0, stream>>>(codes, bank, idx_bg, idx_cl, out);
    }
}

// Round 3
// 591.335 us; speedup vs baseline: 1.1741x; 1.1741x over previous
//
#include <hip/hip_runtime.h>
#include <math.h>

// LocalAggregationLoss, R4: max-MLP register-burst gather.
//   R3 post-mortem: inversion's fixed costs (chain build atomics + 512MB
//   stream) lose to the gather. Back to gathering, but attack the duty
//   cycle decisively:
//   - 2048 blocks (one (batch,list) pair per block) -> 8 blocks/CU supply
//   - per 32-lane group: burst ALL 25 row loads (12.8KB) into registers
//     before any consume; compiler staggers vmcnt waits on drain
//   - ~300KB/CU in flight at burst vs ~80KB avg before
//   - __launch_bounds__(256,3): VGPR cap 168 (25 x float4 = 100 + misc)
//   - per-block partial sum -> d_ws (plain store, no init), tiny k_fin
//     computes log(d1)-log(d2)
// Decision rule: if this ties ~587 us, the scattered-512B wall is the
// memory system itself, not kernel structure.

constexpr int   DIM   = 128;
constexpr int   KN    = 200;
constexpr int   RPG   = 25;              // rows per 32-lane group (200/8)
constexpr float INV_T = 1.0f / 0.07f;

// ---------------- main gather: one (batch, list) per block ----------------

__global__ __launch_bounds__(256, 3)
void k_gather(const float* __restrict__ codes,
              const float* __restrict__ bank,
              const int*   __restrict__ idx_bg,
              const int*   __restrict__ idx_cl,
              float*       __restrict__ dacc,   // [2*batch] partial sums
              int batch)
{
    const int bid  = blockIdx.x;
    const int b    = bid >> 1;
    const int list = bid & 1;
    const int tid  = threadIdx.x;

    const int* __restrict__ ip = list ? idx_cl : idx_bg;

    __shared__ alignas(16) float v[DIM];
    __shared__ int   s_idx[KN];
    __shared__ float wsum[4];
    __shared__ float red[8];
    __shared__ float s_rnorm;

    // ---- preload this block's 200 indices ----
    if (tid < KN) s_idx[tid] = ip[b * KN + tid];

    // ---- normalize codes[b] into LDS ----
    float c  = (tid < DIM) ? codes[b * DIM + tid] : 0.0f;
    float ss = c * c;
    #pragma unroll
    for (int m = 32; m > 0; m >>= 1) ss += __shfl_xor(ss, m, 64);
    if ((tid & 63) == 0) wsum[tid >> 6] = ss;
    __syncthreads();
    if (tid == 0) {
        float t = wsum[0] + wsum[1] + wsum[2] + wsum[3];
        s_rnorm = 1.0f / sqrtf(t);
    }
    __syncthreads();
    if (tid < DIM) v[tid] = c * s_rnorm;
    __syncthreads();

    // ---- burst-gather 25 rows per 32-lane group ----
    const int group = tid >> 5;          // 0..7
    const int lane  = tid & 31;          // 0..31, 16B chunk per lane
    const float4 vv = ((const float4*)v)[lane];
    const int kbase = group * RPG;

    float4 x[RPG];
    #pragma unroll
    for (int u = 0; u < RPG; ++u) {
        const int r = s_idx[kbase + u];
        x[u] = ((const float4*)(bank + (size_t)r * DIM))[lane];
    }

    // ---- drain: dot + group-reduce + exp (staggered vmcnt waits) ----
    float sum = 0.0f;
    #pragma unroll
    for (int u = 0; u < RPG; ++u) {
        float d = x[u].x * vv.x + x[u].y * vv.y + x[u].z * vv.z + x[u].w * vv.w;
        #pragma unroll
        for (int m = 16; m > 0; m >>= 1) d += __shfl_xor(d, m, 64);
        sum += __expf(d * INV_T);
    }

    if (lane == 0) red[group] = sum;
    __syncthreads();
    if (tid == 0) {
        float D = 0.0f;
        #pragma unroll
        for (int g = 0; g < 8; ++g) D += red[g];
        dacc[list * batch + b] = D;      // plain store, no init needed
    }
}

__global__ __launch_bounds__(256)
void k_fin(const float* __restrict__ dacc, float* __restrict__ out, int batch)
{
    const int b = blockIdx.x * blockDim.x + threadIdx.x;
    if (b < batch) out[b] = logf(dacc[b]) - logf(dacc[batch + b]);
}

// ---------------- fallback (R1 structure, known-good) ----------------

constexpr int UF = 5;

__global__ __launch_bounds__(256, 4)
void lal_fallback(const float* __restrict__ codes,
                  const float* __restrict__ bank,
                  const int*   __restrict__ idx_bg,
                  const int*   __restrict__ idx_cl,
                  float*       __restrict__ out)
{
    const int b   = blockIdx.x;
    const int tid = threadIdx.x;

    __shared__ float v[DIM];
    __shared__ int   s_ib[KN];
    __shared__ int   s_ic[KN];
    __shared__ float wsum[4];
    __shared__ float red1[8];
    __shared__ float red2[8];
    __shared__ float s_rnorm;

    if (tid < KN) {
        s_ib[tid] = idx_bg[b * KN + tid];
        s_ic[tid] = idx_cl[b * KN + tid];
    }

    float c  = (tid < DIM) ? codes[b * DIM + tid] : 0.0f;
    float ss = c * c;
    #pragma unroll
    for (int m = 32; m > 0; m >>= 1) ss += __shfl_xor(ss, m, 64);
    if ((tid & 63) == 0) wsum[tid >> 6] = ss;
    __syncthreads();
    if (tid == 0) {
        float t = wsum[0] + wsum[1] + wsum[2] + wsum[3];
        s_rnorm = 1.0f / sqrtf(t);
    }
    __syncthreads();
    if (tid < DIM) v[tid] = c * s_rnorm;
    __syncthreads();

    const int group = tid >> 5;
    const int lane  = tid & 31;
    const float4 vv = ((const float4*)v)[lane];
    const int kbase = group * RPG;

    float sum1 = 0.0f, sum2 = 0.0f;

    #pragma unroll 1
    for (int j = 0; j < RPG; j += UF) {
        float4 x1[UF], x2[UF];
        #pragma unroll
        for (int u = 0; u < UF; ++u) {
            const int r1 = s_ib[kbase + j + u];
            const int r2 = s_ic[kbase + j + u];
            x1[u] = ((const float4*)(bank + (size_t)r1 * DIM))[lane];
            x2[u] = ((const float4*)(bank + (size_t)r2 * DIM))[lane];
        }
        #pragma unroll
        for (int u = 0; u < UF; ++u) {
            float d1 = x1[u].x * vv.x + x1[u].y * vv.y + x1[u].z * vv.z + x1[u].w * vv.w;
            float d2 = x2[u].x * vv.x + x2[u].y * vv.y + x2[u].z * vv.z + x2[u].w * vv.w;
            #pragma unroll
            for (int m = 16; m > 0; m >>= 1) {
                d1 += __shfl_xor(d1, m, 64);
                d2 += __shfl_xor(d2, m, 64);
            }
            sum1 += __expf(d1 * INV_T);
            sum2 += __expf(d2 * INV_T);
        }
    }

    if (lane == 0) { red1[group] = sum1; red2[group] = sum2; }
    __syncthreads();
    if (tid == 0) {
        float D1 = 0.0f, D2 = 0.0f;
        #pragma unroll
        for (int g = 0; g < 8; ++g) { D1 += red1[g]; D2 += red2[g]; }
        out[b] = logf(D1) - logf(D2);
    }
}

// ---------------- launcher ----------------

extern "C" void kernel_launch(void* const* d_in, const int* in_sizes, int n_in,
                              void* d_out, int out_size, void* d_ws, size_t ws_size,
                              hipStream_t stream)
{
    const float* codes  = (const float*)d_in[0];
    const float* bank   = (const float*)d_in[1];
    const int*   idx_bg = (const int*)d_in[2];
    const int*   idx_cl = (const int*)d_in[3];
    float*       out    = (float*)d_out;

    const int batch = in_sizes[0] / DIM;   // 1024

    if (ws_size >= (size_t)(2 * batch) * sizeof(float)) {
        float* dacc = (float*)d_ws;
        k_gather<<<2 * batch, 256, 0, stream>>>(codes, bank, idx_bg, idx_cl,
                                                dacc, batch);
        k_fin<<<(batch + 255) / 256, 256, 0, stream>>>(dacc, out, batch);
    } else {
        lal_fallback<<<batch, 256, 0, stream>>>(codes, bank, idx_bg, idx_cl, out);
    }
}